// Round 12
// baseline (76.236 us; speedup 1.0000x reference)
//
#include <hip/hip_runtime.h>
#include <hip/hip_bf16.h>
#include <math.h>

#define NROWS 8192
#define DIM 128
#define BM 128
#define BN 128
#define CS 16
#define COLS_PER_SLAB (NROWS / CS)     // 512
#define CT_ITERS (COLS_PER_SLAB / BN)  // 4
#define RS (NROWS / BM)                // 64
#define SCALE 1.69864368f              // sqrt(2*log2(e)) -> acc u = sim*log2(e)
#define LN2F 0.69314718056f

typedef __attribute__((ext_vector_type(8))) short bf16x8;
typedef __attribute__((ext_vector_type(4))) float f32x4;

__device__ __forceinline__ void gload16(const void* g, void* l) {
  __builtin_amdgcn_global_load_lds(
      (const __attribute__((address_space(1))) void*)g,
      (__attribute__((address_space(3))) void*)l, 16, 0, 0);
}

// stage a 128x128 bf16 tile into 32KB LDS: linear LDS dest, inverse-swizzled
// GLOBAL source (involution: chunk ^= row&7); reads apply the same XOR.
// wave w covers tile rows [w*32, +32): 8 issues x 1024B.
__device__ __forceinline__ void stage_tile(const ushort* __restrict__ fnb, int row0,
                                           char* tile, int w, int lane) {
  const char* gb = reinterpret_cast<const char*>(fnb);
#pragma unroll
  for (int i = 0; i < 8; ++i) {
    int rl = w * 32 + i * 4 + (lane >> 4);
    int src = ((lane & 15) ^ (rl & 7)) << 4;
    gload16(gb + (size_t)(row0 + rl) * 256 + src, tile + w * 8192 + i * 1024);
  }
}

// ---------------- normalize rows -> bf16 * SCALE; zero losssum[0] ----------------
__global__ __launch_bounds__(256) void k_norm(const float* __restrict__ f,
                                              __hip_bfloat16* __restrict__ fnb,
                                              float* __restrict__ losssum) {
  if (blockIdx.x == 0 && threadIdx.x == 0) losssum[0] = 0.f;
  int wave = threadIdx.x >> 6;
  int lane = threadIdx.x & 63;
  int row = blockIdx.x * 4 + wave;
  const float* src = f + (size_t)row * DIM;
  float v0 = src[lane];
  float v1 = src[lane + 64];
  float ss = v0 * v0 + v1 * v1;
#pragma unroll
  for (int o = 32; o > 0; o >>= 1) ss += __shfl_down(ss, o);
  ss = __shfl(ss, 0);
  float inv = SCALE / fmaxf(sqrtf(ss), 1e-8f);
  __hip_bfloat16* dst = fnb + (size_t)row * DIM;
  dst[lane] = __float2bfloat16(v0 * inv);
  dst[lane + 64] = __float2bfloat16(v1 * inv);
}

// ---------------- MFMA pass ----------------
// Grid (cs, bi): 1024 blocks, 256 thr, 32KB LDS (single B tile) -> 4 blocks/CU.
// A fragments in registers (loaded once from global/L2); B staged via gload_lds.
__global__ __launch_bounds__(256) void k_main(
    const ushort* __restrict__ fnb, const int* __restrict__ lab,
    float* __restrict__ P) {
  __shared__ char lds[BM * 256];  // 32 KB: B tile
  const int t = threadIdx.x;
  const int lane = t & 63;
  const int w = t >> 6;
  const int wm = w >> 1, wn = w & 1;
  const int g = lane >> 4, li16 = lane & 15;
  const int cs = blockIdx.x;
  const int i0 = blockIdx.y * BM;
  const int jslab = cs * COLS_PER_SLAB;

  // stage B0 (async) while loading A fragments + labels
  stage_tile(fnb, jslab, lds, w, lane);

  // A fragments straight from global (L2-resident): rows i0+wm*64+m*16+li16
  bf16x8 af[4][4];
#pragma unroll
  for (int m = 0; m < 4; ++m) {
    const ushort* arow = fnb + (size_t)(i0 + wm * 64 + m * 16 + li16) * DIM + g * 8;
#pragma unroll
    for (int ks = 0; ks < 4; ++ks)
      af[m][ks] = *reinterpret_cast<const bf16x8*>(arow + ks * 32);
  }

  int lr[4][4];
#pragma unroll
  for (int m = 0; m < 4; ++m)
#pragma unroll
    for (int r = 0; r < 4; ++r)
      lr[m][r] = lab[i0 + wm * 64 + m * 16 + g * 4 + r];

  float a_tot[4][4] = {}, a_pos[4][4] = {}, a_sim[4][4] = {};

  __syncthreads();  // drains vmcnt: B0 landed, af loaded

#pragma unroll 1
  for (int ct = 0; ct < CT_ITERS; ++ct) {
    const int j0 = jslab + ct * BN;

    f32x4 acc[4][4];
#pragma unroll
    for (int m = 0; m < 4; ++m)
#pragma unroll
      for (int n = 0; n < 4; ++n) acc[m][n] = (f32x4){0.f, 0.f, 0.f, 0.f};

#pragma unroll
    for (int ks = 0; ks < 4; ++ks) {
      bf16x8 bf[4];
#pragma unroll
      for (int n = 0; n < 4; ++n) {
        int r = wn * 64 + n * 16 + li16;
        int cb = ((ks * 4 + g) ^ (r & 7)) << 4;
        bf[n] = *reinterpret_cast<const bf16x8*>(lds + r * 256 + cb);
      }
#pragma unroll
      for (int m = 0; m < 4; ++m)
#pragma unroll
        for (int n = 0; n < 4; ++n)
          acc[m][n] = __builtin_amdgcn_mfma_f32_16x16x32_bf16(af[m][ks], bf[n], acc[m][n], 0, 0, 0);
    }

    // epilogue: u = sim*log2e; E = 2^u = exp(sim)
#pragma unroll
    for (int n = 0; n < 4; ++n) {
      const int lc = lab[j0 + wn * 64 + n * 16 + li16];
#pragma unroll
      for (int m = 0; m < 4; ++m)
#pragma unroll
        for (int r = 0; r < 4; ++r) {
          float u = acc[m][n][r];
          float E = __builtin_exp2f(u);
          float msk = (lr[m][r] == lc) ? 1.f : 0.f;
          a_tot[m][r] += E;
          a_pos[m][r] = fmaf(msk, E, a_pos[m][r]);
          a_sim[m][r] = fmaf(msk, u, a_sim[m][r]);
        }
    }

    if (ct < CT_ITERS - 1) {
      __syncthreads();                              // all waves done reading B(ct)
      stage_tile(fnb, j0 + BN, lds, w, lane);       // B(ct+1)
      __syncthreads();                              // vmcnt(0) drain + barrier
    }
  }

  // reduce across the 16 li16 lanes (cols)
#pragma unroll
  for (int m = 0; m < 4; ++m)
#pragma unroll
    for (int r = 0; r < 4; ++r)
#pragma unroll
      for (int off = 8; off > 0; off >>= 1) {
        a_tot[m][r] += __shfl_xor(a_tot[m][r], off);
        a_pos[m][r] += __shfl_xor(a_pos[m][r], off);
        a_sim[m][r] += __shfl_xor(a_sim[m][r], off);
      }

  __syncthreads();  // tile done; reuse LDS as scratch
  float* red = reinterpret_cast<float*>(lds);  // [128][2][3]
  if (li16 == 0) {
#pragma unroll
    for (int m = 0; m < 4; ++m)
#pragma unroll
      for (int r = 0; r < 4; ++r) {
        int rl = wm * 64 + m * 16 + g * 4 + r;
        red[(rl * 2 + wn) * 3 + 0] = a_tot[m][r];
        red[(rl * 2 + wn) * 3 + 1] = a_pos[m][r];
        red[(rl * 2 + wn) * 3 + 2] = a_sim[m][r];
      }
  }
  __syncthreads();
  if (wn == 0 && li16 == 0) {
#pragma unroll
    for (int m = 0; m < 4; ++m)
#pragma unroll
      for (int r = 0; r < 4; ++r) {
        int rl = wm * 64 + m * 16 + g * 4 + r;
        float* dst = P + ((size_t)cs * NROWS + (i0 + rl)) * 3;
        dst[0] = red[(rl * 2) * 3 + 0] + red[(rl * 2 + 1) * 3 + 0];
        dst[1] = red[(rl * 2) * 3 + 1] + red[(rl * 2 + 1) * 3 + 1];
        dst[2] = red[(rl * 2) * 3 + 2] + red[(rl * 2 + 1) * 3 + 2];
      }
  }
}

// ---------------- per-row finalize + global sum (in-LDS hist) ----------------
__global__ __launch_bounds__(1024) void k_rowfinal(
    const float* __restrict__ P, const int* __restrict__ lab,
    float* __restrict__ losssum) {
  __shared__ int sh[16][16];
  __shared__ int hist_s[16];
  __shared__ float sred[1024];
  const int t = threadIdx.x;
  const int w = t >> 6;
  if ((t & 63) < 16) sh[w][t & 63] = 0;
  __syncthreads();
#pragma unroll
  for (int it = 0; it < NROWS / 1024; ++it)
    atomicAdd(&sh[w][lab[t + it * 1024]], 1);
  __syncthreads();
  if (t < 16) {
    int s = 0;
#pragma unroll
    for (int x = 0; x < 16; ++x) s += sh[x][t];
    hist_s[t] = s;
  }
  __syncthreads();

  int i = blockIdx.x * 1024 + t;
  float st = 0.f, sp = 0.f, sa = 0.f;
#pragma unroll
  for (int cs = 0; cs < CS; ++cs) {
    const float* p = P + ((size_t)cs * NROWS + i) * 3;
    st += p[0]; sp += p[1]; sa += p[2];
  }
  float cnt = (float)hist_s[lab[i]];
  float negtot = st - sp + cnt;  // negatives' E + positives' exp(0)=1 each
  float li = cnt * logf(negtot) + sp / negtot - LN2F * sa;
  sred[t] = li;
  __syncthreads();
  for (int s2 = 512; s2 > 0; s2 >>= 1) {
    if (t < s2) sred[t] += sred[t + s2];
    __syncthreads();
  }
  if (t == 0) {
    atomicAdd(&losssum[0], sred[0]);
    if (blockIdx.x == 0) {
      int np = 0;
#pragma unroll
      for (int c = 0; c < 10; ++c) np += hist_s[c] * hist_s[c];
      losssum[1] = (float)np;
    }
  }
}

// ---------------- output ----------------
__global__ void k_out(const float* __restrict__ losssum, float* __restrict__ out) {
  if (threadIdx.x == 0) out[0] = losssum[0] / losssum[1];
}

extern "C" void kernel_launch(void* const* d_in, const int* in_sizes, int n_in,
                              void* d_out, int out_size, void* d_ws, size_t ws_size,
                              hipStream_t stream) {
  const float* feat = (const float*)d_in[0];
  const int* lab = (const int*)d_in[1];
  float* out = (float*)d_out;
  char* ws = (char*)d_ws;

  __hip_bfloat16* fnb = (__hip_bfloat16*)ws;                        // 2 MiB
  size_t off = (size_t)NROWS * DIM * 2;
  float* P = (float*)(ws + off); off += (size_t)CS * NROWS * 3 * 4;  // 1.5 MiB
  float* losssum = (float*)(ws + off);

  k_norm<<<NROWS / 4, 256, 0, stream>>>(feat, fnb, losssum);
  k_main<<<dim3(CS, RS), 256, 0, stream>>>((const ushort*)fnb, lab, P);
  k_rowfinal<<<NROWS / 1024, 1024, 0, stream>>>(P, lab, losssum);
  k_out<<<1, 64, 0, stream>>>(losssum, out);
}

// Round 13
// 59.973 us; speedup vs baseline: 1.2712x; 1.2712x over previous
//
#include <hip/hip_runtime.h>
#include <hip/hip_bf16.h>
#include <math.h>

#define NROWS 8192
#define DIM 128
#define BM 128
#define BN 64
#define CS 8
#define COLS_PER_SLAB (NROWS / CS)     // 1024
#define CT_ITERS (COLS_PER_SLAB / BN)  // 16
#define RS (NROWS / BM)                // 64
#define SCALE 1.69864368f              // sqrt(2*log2(e)) -> acc u = sim*log2(e)
#define LN2F 0.69314718056f

typedef __attribute__((ext_vector_type(8))) short bf16x8;
typedef __attribute__((ext_vector_type(4))) float f32x4;

__device__ __forceinline__ void gload16(const void* g, void* l) {
  __builtin_amdgcn_global_load_lds(
      (const __attribute__((address_space(1))) void*)g,
      (__attribute__((address_space(3))) void*)l, 16, 0, 0);
}

// ---- stage 128x128 bf16 (32KB) with 512 threads: 4 chunks/thread ----
// linear LDS dest (wave-uniform base + lane*16), inverse-swizzled global source.
__device__ __forceinline__ void stageA(const ushort* __restrict__ fnb, int row0,
                                       char* tile, int w, int lane) {
  const char* gb = reinterpret_cast<const char*>(fnb);
#pragma unroll
  for (int i = 0; i < 4; ++i) {
    int rl = w * 16 + i * 4 + (lane >> 4);
    int src = ((lane & 15) ^ (rl & 7)) << 4;
    gload16(gb + (size_t)(row0 + rl) * 256 + src, tile + w * 4096 + i * 1024);
  }
}

// ---- stage 64x128 bf16 (16KB) with 512 threads: 2 chunks/thread ----
__device__ __forceinline__ void stageB(const ushort* __restrict__ fnb, int row0,
                                       char* tile, int w, int lane) {
  const char* gb = reinterpret_cast<const char*>(fnb);
#pragma unroll
  for (int i = 0; i < 2; ++i) {
    int rl = w * 8 + i * 4 + (lane >> 4);
    int src = ((lane & 15) ^ (rl & 7)) << 4;
    gload16(gb + (size_t)(row0 + rl) * 256 + src, tile + w * 2048 + i * 1024);
  }
}

// ---------------- normalize rows -> bf16 * SCALE; zero losssum[0] ----------------
__global__ __launch_bounds__(256) void k_norm(const float* __restrict__ f,
                                              __hip_bfloat16* __restrict__ fnb,
                                              float* __restrict__ losssum) {
  if (blockIdx.x == 0 && threadIdx.x == 0) losssum[0] = 0.f;
  int wave = threadIdx.x >> 6;
  int lane = threadIdx.x & 63;
  int row = blockIdx.x * 4 + wave;
  const float* src = f + (size_t)row * DIM;
  float v0 = src[lane];
  float v1 = src[lane + 64];
  float ss = v0 * v0 + v1 * v1;
#pragma unroll
  for (int o = 32; o > 0; o >>= 1) ss += __shfl_down(ss, o);
  ss = __shfl(ss, 0);
  float inv = SCALE / fmaxf(sqrtf(ss), 1e-8f);
  __hip_bfloat16* dst = fnb + (size_t)row * DIM;
  dst[lane] = __float2bfloat16(v0 * inv);
  dst[lane + 64] = __float2bfloat16(v1 * inv);
}

// ---------------- MFMA pass ----------------
// 512 thr = 8 waves (wm 2 x wn 4); per-wave C = 64x16. LDS: A 32K + B dbuf 2x16K.
// T3 2-phase: stage(ct+1) -> compute(ct) -> vmcnt(0)+barrier.
__global__ __launch_bounds__(512) void k_main(
    const ushort* __restrict__ fnb, const int* __restrict__ lab,
    float* __restrict__ P) {
  __shared__ char lds[65536];
  char* Abase = lds;

  const int t = threadIdx.x;
  const int lane = t & 63;
  const int w = t >> 6;
  const int wm = w >> 2;    // 0..1
  const int wn = w & 3;     // 0..3
  const int g = lane >> 4, li16 = lane & 15;
  const int cs = blockIdx.x;
  const int i0 = blockIdx.y * BM;
  const int jslab = cs * COLS_PER_SLAB;

  // prologue: stage A and B0
  stageA(fnb, i0, Abase, w, lane);
  stageB(fnb, jslab, lds + 32768, w, lane);

  // labels of this thread's C rows: row = wm*64 + m*16 + g*4 + r
  int lr[4][4];
#pragma unroll
  for (int m = 0; m < 4; ++m)
#pragma unroll
    for (int r = 0; r < 4; ++r)
      lr[m][r] = lab[i0 + wm * 64 + m * 16 + g * 4 + r];

  float a_tot[4][4] = {}, a_pos[4][4] = {}, a_sim[4][4] = {};

  __syncthreads();  // drains vmcnt: A and B0 landed

#pragma unroll 1
  for (int ct = 0; ct < CT_ITERS; ++ct) {
    const int j0 = jslab + ct * BN;
    char* cur = lds + 32768 + ((ct & 1) << 14);
    if (ct < CT_ITERS - 1)
      stageB(fnb, j0 + BN, lds + 32768 + (((ct + 1) & 1) << 14), w, lane);

    f32x4 acc[4];
#pragma unroll
    for (int m = 0; m < 4; ++m) acc[m] = (f32x4){0.f, 0.f, 0.f, 0.f};

#pragma unroll
    for (int ks = 0; ks < 4; ++ks) {
      bf16x8 bf;
      {
        int r2 = wn * 16 + li16;
        int cb = ((ks * 4 + g) ^ (r2 & 7)) << 4;
        bf = *reinterpret_cast<const bf16x8*>(cur + r2 * 256 + cb);
      }
      bf16x8 af[4];
#pragma unroll
      for (int m = 0; m < 4; ++m) {
        int r = wm * 64 + m * 16 + li16;
        int cb = ((ks * 4 + g) ^ (r & 7)) << 4;
        af[m] = *reinterpret_cast<const bf16x8*>(Abase + r * 256 + cb);
      }
#pragma unroll
      for (int m = 0; m < 4; ++m)
        acc[m] = __builtin_amdgcn_mfma_f32_16x16x32_bf16(af[m], bf, acc[m], 0, 0, 0);
    }

    // epilogue: u = sim*log2e; E = 2^u = exp(sim)   (covers in-flight stage loads)
    const int lc = lab[j0 + wn * 16 + li16];
#pragma unroll
    for (int m = 0; m < 4; ++m)
#pragma unroll
      for (int r = 0; r < 4; ++r) {
        float u = acc[m][r];
        float E = __builtin_exp2f(u);
        float msk = (lr[m][r] == lc) ? 1.f : 0.f;
        a_tot[m][r] += E;
        a_pos[m][r] = fmaf(msk, E, a_pos[m][r]);
        a_sim[m][r] = fmaf(msk, u, a_sim[m][r]);
      }

    asm volatile("s_waitcnt vmcnt(0)" ::: "memory");  // B(ct+1) landed (covered)
    __builtin_amdgcn_s_barrier();
  }

  // reduce across the 16 li16 lanes (cols of this wave's 16-col slice)
#pragma unroll
  for (int m = 0; m < 4; ++m)
#pragma unroll
    for (int r = 0; r < 4; ++r)
#pragma unroll
      for (int off = 8; off > 0; off >>= 1) {
        a_tot[m][r] += __shfl_xor(a_tot[m][r], off);
        a_pos[m][r] += __shfl_xor(a_pos[m][r], off);
        a_sim[m][r] += __shfl_xor(a_sim[m][r], off);
      }

  __syncthreads();  // tiles done; reuse LDS as scratch
  float(*red)[4][3] = reinterpret_cast<float(*)[4][3]>(lds);  // [128][wn][3]
  if (li16 == 0) {
#pragma unroll
    for (int m = 0; m < 4; ++m)
#pragma unroll
      for (int r = 0; r < 4; ++r) {
        int rl = wm * 64 + m * 16 + g * 4 + r;
        red[rl][wn][0] = a_tot[m][r];
        red[rl][wn][1] = a_pos[m][r];
        red[rl][wn][2] = a_sim[m][r];
      }
  }
  __syncthreads();
  if (wn == 0 && li16 == 0) {
#pragma unroll
    for (int m = 0; m < 4; ++m)
#pragma unroll
      for (int r = 0; r < 4; ++r) {
        int rl = wm * 64 + m * 16 + g * 4 + r;
        float* dst = P + ((size_t)cs * NROWS + (i0 + rl)) * 3;
        dst[0] = red[rl][0][0] + red[rl][1][0] + red[rl][2][0] + red[rl][3][0];
        dst[1] = red[rl][0][1] + red[rl][1][1] + red[rl][2][1] + red[rl][3][1];
        dst[2] = red[rl][0][2] + red[rl][1][2] + red[rl][2][2] + red[rl][3][2];
      }
  }
}

// ---------------- per-row finalize + global sum (in-LDS hist) ----------------
__global__ __launch_bounds__(1024) void k_rowfinal(
    const float* __restrict__ P, const int* __restrict__ lab,
    float* __restrict__ losssum) {
  __shared__ int sh[16][16];
  __shared__ int hist_s[16];
  __shared__ float sred[1024];
  const int t = threadIdx.x;
  const int w = t >> 6;
  if ((t & 63) < 16) sh[w][t & 63] = 0;
  __syncthreads();
#pragma unroll
  for (int it = 0; it < NROWS / 1024; ++it)
    atomicAdd(&sh[w][lab[t + it * 1024]], 1);
  __syncthreads();
  if (t < 16) {
    int s = 0;
#pragma unroll
    for (int x = 0; x < 16; ++x) s += sh[x][t];
    hist_s[t] = s;
  }
  __syncthreads();

  int i = blockIdx.x * 1024 + t;
  float st = 0.f, sp = 0.f, sa = 0.f;
#pragma unroll
  for (int cs = 0; cs < CS; ++cs) {
    const float* p = P + ((size_t)cs * NROWS + i) * 3;
    st += p[0]; sp += p[1]; sa += p[2];
  }
  float cnt = (float)hist_s[lab[i]];
  float negtot = st - sp + cnt;  // negatives' E + positives' exp(0)=1 each
  float li = cnt * logf(negtot) + sp / negtot - LN2F * sa;
  sred[t] = li;
  __syncthreads();
  for (int s2 = 512; s2 > 0; s2 >>= 1) {
    if (t < s2) sred[t] += sred[t + s2];
    __syncthreads();
  }
  if (t == 0) {
    atomicAdd(&losssum[0], sred[0]);
    if (blockIdx.x == 0) {
      int np = 0;
#pragma unroll
      for (int c = 0; c < 10; ++c) np += hist_s[c] * hist_s[c];
      losssum[1] = (float)np;
    }
  }
}

// ---------------- output ----------------
__global__ void k_out(const float* __restrict__ losssum, float* __restrict__ out) {
  if (threadIdx.x == 0) out[0] = losssum[0] / losssum[1];
}

extern "C" void kernel_launch(void* const* d_in, const int* in_sizes, int n_in,
                              void* d_out, int out_size, void* d_ws, size_t ws_size,
                              hipStream_t stream) {
  const float* feat = (const float*)d_in[0];
  const int* lab = (const int*)d_in[1];
  float* out = (float*)d_out;
  char* ws = (char*)d_ws;

  __hip_bfloat16* fnb = (__hip_bfloat16*)ws;                        // 2 MiB
  size_t off = (size_t)NROWS * DIM * 2;
  float* P = (float*)(ws + off); off += (size_t)CS * NROWS * 3 * 4;  // 768 KiB
  float* losssum = (float*)(ws + off);

  k_norm<<<NROWS / 4, 256, 0, stream>>>(feat, fnb, losssum);
  k_main<<<dim3(CS, RS), 512, 0, stream>>>((const ushort*)fnb, lab, P);
  k_rowfinal<<<NROWS / 1024, 1024, 0, stream>>>(P, lab, losssum);
  k_out<<<1, 64, 0, stream>>>(losssum, out);
}

// Round 14
// 52.148 us; speedup vs baseline: 1.4619x; 1.1501x over previous
//
#include <hip/hip_runtime.h>
#include <hip/hip_bf16.h>
#include <math.h>

#define NROWS 8192
#define DIM 128
#define BM 128
#define BN 128
#define CS 8
#define COLS_PER_SLAB (NROWS / CS)     // 1024
#define CT_ITERS (COLS_PER_SLAB / BN)  // 8
#define RS (NROWS / BM)                // 64
#define SCALE 1.69864368f              // sqrt(2*log2(e)) -> acc u = sim*log2(e)
#define LN2F 0.69314718056f

typedef __attribute__((ext_vector_type(8))) short bf16x8;
typedef __attribute__((ext_vector_type(4))) float f32x4;

#define VMCNT0 asm volatile("s_waitcnt vmcnt(0)" ::: "memory")
#define BAR __builtin_amdgcn_s_barrier()

__device__ __forceinline__ void gload16(const void* g, void* l) {
  __builtin_amdgcn_global_load_lds(
      (const __attribute__((address_space(1))) void*)g,
      (__attribute__((address_space(3))) void*)l, 16, 0, 0);
}

// stage 128x128 bf16 (32KB) with 256 threads: linear LDS dest, inverse-swizzled
// global source (chunk c stored at c^(row&7); reads apply same XOR). 8 issues.
__device__ __forceinline__ void stageA(const ushort* __restrict__ fnb, int row0,
                                       char* tile, int t) {
  const char* gb = reinterpret_cast<const char*>(fnb) + (size_t)row0 * 256;
#pragma unroll
  for (int i = 0; i < 8; ++i) {
    int q = t + 256 * i;         // 16B chunk id, 0..2047
    int row = q >> 4, c = q & 15;
    gload16(gb + row * 256 + ((c ^ (row & 7)) << 4), tile + q * 16);
  }
}

// stage a K-half: 128 rows x 64 cols bf16 (16KB). Row stride in buf = 128B. 4 issues.
__device__ __forceinline__ void stageBh(const ushort* __restrict__ fnb, int j0, int kh,
                                        char* buf, int t) {
  const char* gb = reinterpret_cast<const char*>(fnb) + (size_t)j0 * 256 + kh * 128;
#pragma unroll
  for (int i = 0; i < 4; ++i) {
    int q = t + 256 * i;         // 0..1023
    int row = q >> 3, c = q & 7;
    gload16(gb + row * 256 + ((c ^ (row & 7)) << 4), buf + q * 16);
  }
}

// ---------------- normalize rows -> bf16 * SCALE; zero losssum[0] ----------------
__global__ __launch_bounds__(256) void k_norm(const float* __restrict__ f,
                                              __hip_bfloat16* __restrict__ fnb,
                                              float* __restrict__ losssum) {
  if (blockIdx.x == 0 && threadIdx.x == 0) losssum[0] = 0.f;
  int wave = threadIdx.x >> 6;
  int lane = threadIdx.x & 63;
  int row = blockIdx.x * 4 + wave;
  const float* src = f + (size_t)row * DIM;
  float v0 = src[lane];
  float v1 = src[lane + 64];
  float ss = v0 * v0 + v1 * v1;
#pragma unroll
  for (int o = 32; o > 0; o >>= 1) ss += __shfl_down(ss, o);
  ss = __shfl(ss, 0);
  float inv = SCALE / fmaxf(sqrtf(ss), 1e-8f);
  __hip_bfloat16* dst = fnb + (size_t)row * DIM;
  dst[lane] = __float2bfloat16(v0 * inv);
  dst[lane + 64] = __float2bfloat16(v1 * inv);
}

// ---------------- MFMA pass ----------------
// 256 thr = 4 waves (2x2), per-wave C = 64x64. LDS: A 32K + B K-half dbuf 2x16K.
// Pipeline: per half-phase {stage next half -> ds_reads+MFMA(+epilogue) -> vmcnt(0)+bar}.
__global__ __launch_bounds__(256, 2) void k_main(
    const ushort* __restrict__ fnb, const int* __restrict__ lab,
    float* __restrict__ P, float* __restrict__ Ps) {
  __shared__ char lds[65536];
  char* Bbuf0 = lds + 32768;
  char* Bbuf1 = lds + 49152;

  const int t = threadIdx.x;
  const int lane = t & 63;
  const int w = t >> 6;
  const int wm = w >> 1, wn = w & 1;
  const int g = lane >> 4, li16 = lane & 15;
  const int cs = blockIdx.x;
  const int i0 = blockIdx.y * BM;
  const int jslab = cs * COLS_PER_SLAB;

  // prologue: stage A (once) and B(ct=0, kh=0)
  stageA(fnb, i0, lds, t);
  stageBh(fnb, jslab, 0, Bbuf0, t);

  // labels of this thread's C rows: row = wm*64 + m*16 + g*4 + r
  int lr[4][4];
#pragma unroll
  for (int m = 0; m < 4; ++m)
#pragma unroll
    for (int r = 0; r < 4; ++r)
      lr[m][r] = lab[i0 + wm * 64 + m * 16 + g * 4 + r];

  float a_tot[4][4] = {}, a_pos[4][4] = {};
  float s_sim = 0.f;

  VMCNT0;
  BAR;

#define COMPUTE(buf, khA)                                                        \
  _Pragma("unroll") for (int ks = 0; ks < 2; ++ks) {                             \
    const int kc = ((khA)*2 + ks) * 4 + g;                                       \
    bf16x8 af[4], bf[4];                                                         \
    _Pragma("unroll") for (int m = 0; m < 4; ++m) {                              \
      int r = wm * 64 + m * 16 + li16;                                           \
      af[m] = *reinterpret_cast<const bf16x8*>(lds + r * 256 + ((kc ^ (r & 7)) << 4)); \
    }                                                                            \
    _Pragma("unroll") for (int n = 0; n < 4; ++n) {                              \
      int r2 = wn * 64 + n * 16 + li16;                                          \
      bf[n] = *reinterpret_cast<const bf16x8*>((buf) + r2 * 128 + (((ks * 4 + g) ^ (r2 & 7)) << 4)); \
    }                                                                            \
    _Pragma("unroll") for (int m = 0; m < 4; ++m)                                \
      _Pragma("unroll") for (int n = 0; n < 4; ++n)                              \
        acc[m][n] = __builtin_amdgcn_mfma_f32_16x16x32_bf16(af[m], bf[n], acc[m][n], 0, 0, 0); \
  }

#pragma unroll 1
  for (int ct = 0; ct < CT_ITERS; ++ct) {
    const int j0 = jslab + ct * BN;

    f32x4 acc[4][4];
#pragma unroll
    for (int m = 0; m < 4; ++m)
#pragma unroll
      for (int n = 0; n < 4; ++n) acc[m][n] = (f32x4){0.f, 0.f, 0.f, 0.f};

    // phase 0: stage (ct, kh=1) -> Bbuf1 ; compute Bbuf0 (A chunks 0..1)
    stageBh(fnb, j0, 1, Bbuf1, t);
    COMPUTE(Bbuf0, 0);
    VMCNT0;
    BAR;

    // phase 1: stage (ct+1, kh=0) -> Bbuf0 ; compute Bbuf1 (A chunks 2..3); epilogue
    if (ct + 1 < CT_ITERS) stageBh(fnb, j0 + BN, 0, Bbuf0, t);
    COMPUTE(Bbuf1, 1);

    // epilogue: u = sim*log2e; E = 2^u = exp(sim)
#pragma unroll
    for (int n = 0; n < 4; ++n) {
      const int lc = lab[j0 + wn * 64 + n * 16 + li16];
#pragma unroll
      for (int m = 0; m < 4; ++m)
#pragma unroll
        for (int r = 0; r < 4; ++r) {
          float u = acc[m][n][r];
          float E = __builtin_exp2f(u);
          float msk = (lr[m][r] == lc) ? 1.f : 0.f;
          a_tot[m][r] += E;
          a_pos[m][r] = fmaf(msk, E, a_pos[m][r]);
          s_sim = fmaf(msk, u, s_sim);
        }
    }
    VMCNT0;
    BAR;
  }
#undef COMPUTE

  // reduce row stats across the 16 li16 lanes (cols)
#pragma unroll
  for (int m = 0; m < 4; ++m)
#pragma unroll
    for (int r = 0; r < 4; ++r)
#pragma unroll
      for (int off = 8; off > 0; off >>= 1) {
        a_tot[m][r] += __shfl_xor(a_tot[m][r], off);
        a_pos[m][r] += __shfl_xor(a_pos[m][r], off);
      }
  // s_sim: full-wave reduce
#pragma unroll
  for (int off = 32; off > 0; off >>= 1) s_sim += __shfl_xor(s_sim, off);

  __syncthreads();  // tiles done; reuse LDS as scratch
  float(*red)[2][2] = reinterpret_cast<float(*)[2][2]>(lds);  // [128][wn][2]
  float* sS = reinterpret_cast<float*>(lds + 4096);
  if (li16 == 0) {
#pragma unroll
    for (int m = 0; m < 4; ++m)
#pragma unroll
      for (int r = 0; r < 4; ++r) {
        int rl = wm * 64 + m * 16 + g * 4 + r;
        red[rl][wn][0] = a_tot[m][r];
        red[rl][wn][1] = a_pos[m][r];
      }
  }
  if (lane == 0) sS[w] = s_sim;
  __syncthreads();
  if (wn == 0 && li16 == 0) {
#pragma unroll
    for (int m = 0; m < 4; ++m)
#pragma unroll
      for (int r = 0; r < 4; ++r) {
        int rl = wm * 64 + m * 16 + g * 4 + r;
        float* dst = P + ((size_t)cs * NROWS + (i0 + rl)) * 2;
        dst[0] = red[rl][0][0] + red[rl][1][0];
        dst[1] = red[rl][0][1] + red[rl][1][1];
      }
  }
  if (t == 0) Ps[blockIdx.y * CS + cs] = sS[0] + sS[1] + sS[2] + sS[3];
}

// ---------------- per-row finalize + global sum (in-LDS hist) ----------------
__global__ __launch_bounds__(1024) void k_rowfinal(
    const float* __restrict__ P, const int* __restrict__ lab,
    float* __restrict__ losssum) {
  __shared__ int sh[16][16];
  __shared__ int hist_s[16];
  __shared__ float sred[1024];
  const int t = threadIdx.x;
  const int w = t >> 6;
  if ((t & 63) < 16) sh[w][t & 63] = 0;
  __syncthreads();
#pragma unroll
  for (int it = 0; it < NROWS / 1024; ++it)
    atomicAdd(&sh[w][lab[t + it * 1024]], 1);
  __syncthreads();
  if (t < 16) {
    int s = 0;
#pragma unroll
    for (int x = 0; x < 16; ++x) s += sh[x][t];
    hist_s[t] = s;
  }
  __syncthreads();

  int i = blockIdx.x * 1024 + t;
  float st = 0.f, sp = 0.f;
#pragma unroll
  for (int cs = 0; cs < CS; ++cs) {
    const float* p = P + ((size_t)cs * NROWS + i) * 2;
    st += p[0];
    sp += p[1];
  }
  float cnt = (float)hist_s[lab[i]];
  float negtot = st - sp + cnt;  // negatives' E + positives' exp(0)=1 each
  float li = cnt * logf(negtot) + sp / negtot;
  sred[t] = li;
  __syncthreads();
  for (int s2 = 512; s2 > 0; s2 >>= 1) {
    if (t < s2) sred[t] += sred[t + s2];
    __syncthreads();
  }
  if (t == 0) {
    atomicAdd(&losssum[0], sred[0]);
    if (blockIdx.x == 0) {
      int np = 0;
#pragma unroll
      for (int c = 0; c < 10; ++c) np += hist_s[c] * hist_s[c];
      losssum[1] = (float)np;
    }
  }
}

// ---------------- output: fold global sim-sum, divide ----------------
__global__ __launch_bounds__(512) void k_out(const float* __restrict__ losssum,
                                             const float* __restrict__ Ps,
                                             float* __restrict__ out) {
  __shared__ float sred[512];
  const int t = threadIdx.x;
  sred[t] = Ps[t];
  __syncthreads();
  for (int s = 256; s > 0; s >>= 1) {
    if (t < s) sred[t] += sred[t + s];
    __syncthreads();
  }
  if (t == 0) out[0] = (losssum[0] - LN2F * sred[0]) / losssum[1];
}

extern "C" void kernel_launch(void* const* d_in, const int* in_sizes, int n_in,
                              void* d_out, int out_size, void* d_ws, size_t ws_size,
                              hipStream_t stream) {
  const float* feat = (const float*)d_in[0];
  const int* lab = (const int*)d_in[1];
  float* out = (float*)d_out;
  char* ws = (char*)d_ws;

  __hip_bfloat16* fnb = (__hip_bfloat16*)ws;                         // 2 MiB
  size_t off = (size_t)NROWS * DIM * 2;
  float* P = (float*)(ws + off); off += (size_t)CS * NROWS * 2 * 4;  // 512 KiB
  float* Ps = (float*)(ws + off); off += (size_t)CS * RS * 4;        // 2 KiB
  float* losssum = (float*)(ws + off);

  k_norm<<<NROWS / 4, 256, 0, stream>>>(feat, fnb, losssum);
  k_main<<<dim3(CS, RS), 256, 0, stream>>>((const ushort*)fnb, lab, P, Ps);
  k_rowfinal<<<NROWS / 1024, 1024, 0, stream>>>(P, lab, losssum);
  k_out<<<1, 512, 0, stream>>>(losssum, Ps, out);
}